// Round 3
// baseline (257.613 us; speedup 1.0000x reference)
//
#include <hip/hip_runtime.h>
#include <stdint.h>

#define NA 98304
#define NT 1024
#define NC 21
#define ACH 384          // anchor chunks of 256
#define TCH 4            // target chunks of 256

// ws layout:
//   [0]   double cls_sum
//   [8]   int    n_pos
//   [12]  int    done_cnt
//   [16]         u64 tkeys[NT]    (8 KB)
//   [16+8192]    u64 akeys[NA]    (768 KB)
//   [16+8192+786432] float tarea[NT]  (written by k_prep, no zeroing needed)
// memset covers [0, 16 + 8192 + NA*8)

__global__ __launch_bounds__(1024) void k_prep(
    const float4* __restrict__ tboxes, float* __restrict__ tarea)
{
    const int t = threadIdx.x;
    const float4 tb = tboxes[t];
    tarea[t] = (tb.z - tb.x) * (tb.w - tb.y);
}

__global__ __launch_bounds__(256) void k_match(
    const float4* __restrict__ anchors,
    const float4* __restrict__ tboxes,
    const float* __restrict__ tarea,
    unsigned long long* __restrict__ akeys,
    unsigned long long* __restrict__ tkeys)
{
    const int tid   = threadIdx.x;
    const int a     = blockIdx.x * 256 + tid;
    const int tbase = blockIdx.y * 256;

    const float4 ab = anchors[a];
    const float area_a = (ab.z - ab.x) * (ab.w - ab.y);

    float bi = 0.f, bu = 1.f;   // best (inter, union) => iou 0
    int bidx = 0;

    #pragma unroll 8
    for (int t = 0; t < 256; ++t) {
        // wave-uniform address -> scalar (SMEM) loads, co-issue with VALU
        const float4 tb = tboxes[tbase + t];
        const float  sa = tarea[tbase + t];
        const float lx = fmaxf(ab.x, tb.x);
        const float ly = fmaxf(ab.y, tb.y);
        const float rx = fminf(ab.z, tb.z);
        const float ry = fminf(ab.w, tb.w);
        const float w  = fmaxf(rx - lx, 0.f);
        const float h  = fmaxf(ry - ly, 0.f);
        const float inter = w * h;
        const float uni = (area_a + sa) - inter;
        // target-side: any pair with iou >= 0.5 is pushed (rare branch);
        // below-threshold pairs can never contribute to reg loss
        if (inter + inter >= uni) {
            const float iou = inter / uni;   // same fp32 rounding as reference
            const unsigned long long key =
                ((unsigned long long)__float_as_uint(iou) << 32) |
                (unsigned long long)(0xFFFFFFFFu - (unsigned int)a); // smaller a wins ties
            atomicMax(&tkeys[tbase + t], key);
        }
        // anchor-side running max via exact cross-mult compare
        const bool gt = inter * bu > bi * uni;
        bi   = gt ? inter : bi;
        bu   = gt ? uni   : bu;
        bidx = gt ? t     : bidx;
    }
    if (bi + bi >= bu) {         // chunk-partial max >= 0.5: only these matter
        const float iou = bi / bu;
        const unsigned int tg = (unsigned int)(tbase + bidx);
        const unsigned long long key =
            ((unsigned long long)__float_as_uint(iou) << 32) |
            (unsigned long long)(0xFFFFFFFFu - tg);      // smaller t wins ties
        atomicMax(&akeys[a], key);
    }
}

__device__ __forceinline__ float smooth_l1(float d) {
    const float ad = fabsf(d);
    return (ad < 1.f) ? 0.5f * d * d : ad - 0.5f;
}

// one block per 256 anchors; last-finishing block computes reg loss + writes out
__global__ __launch_bounds__(256) void k_cls_final(
    const float* __restrict__ preds,
    const int* __restrict__ tlabels,
    const float4* __restrict__ anchors,
    const float4* __restrict__ tboxes,
    const float4* __restrict__ bpreds,
    const unsigned long long* __restrict__ akeys,
    const unsigned long long* __restrict__ tkeys,
    double* __restrict__ cls_sum,
    int* __restrict__ n_pos,
    int* __restrict__ done_cnt,
    float* __restrict__ out)
{
    __shared__ int s_lab[256];
    __shared__ float s_red[8];
    __shared__ int s_flag;
    __shared__ double s_cls;
    __shared__ int s_np;

    const int tid = threadIdx.x;
    const int blk = blockIdx.x;
    const int a   = blk * 256 + tid;

    const unsigned long long akey = akeys[a];
    int lab = -1;
    if (akey != 0ull) {
        const unsigned int t = 0xFFFFFFFFu - (unsigned int)(akey & 0xFFFFFFFFull);
        lab = tlabels[t];
    }
    s_lab[tid] = lab;
    const unsigned long long bal = __ballot(akey != 0ull);
    if ((tid & 63) == 0) atomicAdd(n_pos, (int)__popcll(bal));
    __syncthreads();

    // focal loss over this block's 256 anchors x 21 classes (contiguous, coalesced)
    float acc = 0.f;
    const int base = blk * (256 * NC);
    for (int e = tid; e < 256 * NC; e += 256) {
        const int al = e / NC;            // magic-mul div
        const int c  = e - al * NC;
        const float x  = preds[base + e];
        const float t  = (s_lab[al] == c) ? 1.f : 0.f;
        const float ax = fabsf(x);
        const float u  = __expf(-ax);
        const float ce = fmaxf(x, 0.f) - x * t + __logf(1.f + u);
        const float p  = (x >= 0.f ? 1.f : u) / (1.f + u);
        const float pt = p * t + (1.f - p) * (1.f - t);
        const float at = 0.25f * t + 0.75f * (1.f - t);
        const float om = 1.f - pt;
        acc += at * om * om * ce;
    }
    for (int o = 32; o > 0; o >>= 1) acc += __shfl_down(acc, o);
    const int lane = tid & 63, wid = tid >> 6;
    if (lane == 0) s_red[wid] = acc;
    __syncthreads();
    if (tid == 0) {
        atomicAdd(cls_sum, (double)(s_red[0] + s_red[1] + s_red[2] + s_red[3]));
        __threadfence();
        const int old = atomicAdd(done_cnt, 1);
        s_flag = (old == (int)gridDim.x - 1);
    }
    __syncthreads();
    if (!s_flag) return;

    // ---- last block: regression loss + final combine ----
    if (tid == 0) {
        s_cls = atomicAdd(cls_sum, 0.0);  // coherent device-scope read
        s_np  = atomicAdd(n_pos, 0);
    }
    __syncthreads();

    float s = 0.f, m = 0.f;
    #pragma unroll
    for (int j = 0; j < 4; ++j) {
        const int t = tid + 256 * j;
        const unsigned long long key = tkeys[t];
        if (key != 0ull) {
            const unsigned int ga = 0xFFFFFFFFu - (unsigned int)(key & 0xFFFFFFFFull);
            const float4 tb = tboxes[t];
            const float4 abx = anchors[ga];
            const float4 pb = bpreds[ga];
            const float bw = tb.z - tb.x, bh = tb.w - tb.y;
            const float bcx = tb.x + 0.5f * bw, bcy = tb.y + 0.5f * bh;
            const float aw = abx.z - abx.x, ah = abx.w - abx.y;
            const float acx = abx.x + 0.5f * aw, acy = abx.y + 0.5f * ah;
            const float tx = (bcx - acx) / aw;
            const float ty = (bcy - acy) / ah;
            const float tw = logf(fmaxf(bw, 1e-8f) / aw);
            const float th = logf(fmaxf(bh, 1e-8f) / ah);
            s = smooth_l1(pb.x - tx) + smooth_l1(pb.y - ty) +
                smooth_l1(pb.z - tw) + smooth_l1(pb.w - th);
            m = 1.f;
        }
    }
    for (int o = 32; o > 0; o >>= 1) {
        s += __shfl_down(s, o);
        m += __shfl_down(m, o);
    }
    __syncthreads();          // s_red reuse
    if (lane == 0) { s_red[wid] = s; s_red[4 + wid] = m; }
    __syncthreads();
    if (tid == 0) {
        const float rs = s_red[0] + s_red[1] + s_red[2] + s_red[3];
        const float rm = s_red[4] + s_red[5] + s_red[6] + s_red[7];
        const float cls = (float)(s_cls / (double)s_np);
        const float reg = rs / (fmaxf(rm, 1.f) * 4.f);
        out[0] = cls + reg;
        out[1] = cls;
        out[2] = reg;
    }
}

extern "C" void kernel_launch(void* const* d_in, const int* in_sizes, int n_in,
                              void* d_out, int out_size, void* d_ws, size_t ws_size,
                              hipStream_t stream) {
    const float*  cls_preds = (const float*)d_in[0];
    const float4* bpreds    = (const float4*)d_in[1];
    const float4* anchors   = (const float4*)d_in[2];
    const float4* tboxes    = (const float4*)d_in[3];
    const int*    tlabels   = (const int*)d_in[4];

    char* ws = (char*)d_ws;
    double* cls_sum = (double*)(ws + 0);
    int*    n_pos   = (int*)(ws + 8);
    int*    done    = (int*)(ws + 12);
    unsigned long long* tkeys = (unsigned long long*)(ws + 16);
    unsigned long long* akeys = (unsigned long long*)(ws + 16 + NT * 8);
    float*  tarea   = (float*)(ws + 16 + NT * 8 + NA * 8);

    hipMemsetAsync(d_ws, 0, 16 + NT * 8 + NA * 8, stream);

    k_prep<<<1, NT, 0, stream>>>(tboxes, tarea);
    k_match<<<dim3(ACH, TCH), 256, 0, stream>>>(anchors, tboxes, tarea, akeys, tkeys);
    k_cls_final<<<NA / 256, 256, 0, stream>>>(cls_preds, tlabels, anchors, tboxes,
                                              bpreds, akeys, tkeys,
                                              cls_sum, n_pos, done, (float*)d_out);
}

// Round 4
// 255.198 us; speedup vs baseline: 1.0095x; 1.0095x over previous
//
#include <hip/hip_runtime.h>
#include <stdint.h>

#define NA 98304
#define NT 1024
#define NC 21
#define ACH 384          // anchor chunks of 256
#define TCH 4            // target chunks of 256

// ws layout:
//   [0]   double cls_sum
//   [8]   int    n_pos
//   [12]  int    done_cnt
//   [16]         u64 tkeys[NT]    (8 KB)
//   [16+8192]    u64 akeys[NA]    (768 KB)
// memset covers [0, 16 + 8192 + NA*8)

__global__ __launch_bounds__(256, 8) void k_match(
    const float4* __restrict__ anchors,
    const float4* __restrict__ tboxes,
    unsigned long long* __restrict__ akeys,
    unsigned long long* __restrict__ tkeys)
{
    __shared__ float4 s_t[256];

    const int tid   = threadIdx.x;
    const int a     = blockIdx.x * 256 + tid;
    const int tbase = blockIdx.y * 256;

    s_t[tid] = tboxes[tbase + tid];
    const float4 ab = anchors[a];
    __syncthreads();

    const float area_a = (ab.z - ab.x) * (ab.w - ab.y);

    // Single pass: only pairs with iou >= 0.5 can influence EITHER reduction
    // (anchor-side: max<0.5 => label -1; target-side: max<0.5 => t_mask=0).
    // So no running max needed — push thresholded pairs to both key arrays.
    #pragma unroll 8
    for (int t = 0; t < 256; ++t) {
        const float4 tb = s_t[t];          // ds_read_b128 broadcast
        const float lx = fmaxf(ab.x, tb.x);
        const float ly = fmaxf(ab.y, tb.y);
        const float rx = fminf(ab.z, tb.z);
        const float ry = fminf(ab.w, tb.w);
        const float w  = fmaxf(rx - lx, 0.f);
        const float h  = fmaxf(ry - ly, 0.f);
        const float inter = w * h;
        const float sa  = (tb.z - tb.x) * (tb.w - tb.y);  // recompute: VALU < LDS
        const float uni = (area_a + sa) - inter;
        if (__builtin_expect(inter + inter >= uni, 0)) {  // iou >= 0.5, rare
            const float iou = inter / uni;  // same fp32 rounding as reference
            const unsigned long long hi = (unsigned long long)__float_as_uint(iou) << 32;
            // target-side key: smaller anchor wins ties
            atomicMax(&tkeys[tbase + t],
                      hi | (unsigned long long)(0xFFFFFFFFu - (unsigned int)a));
            // anchor-side key: smaller target wins ties
            atomicMax(&akeys[a],
                      hi | (unsigned long long)(0xFFFFFFFFu - (unsigned int)(tbase + t)));
        }
    }
}

__device__ __forceinline__ float smooth_l1(float d) {
    const float ad = fabsf(d);
    return (ad < 1.f) ? 0.5f * d * d : ad - 0.5f;
}

// one block per 256 anchors; last-finishing block computes reg loss + writes out
__global__ __launch_bounds__(256, 8) void k_cls_final(
    const float* __restrict__ preds,
    const int* __restrict__ tlabels,
    const float4* __restrict__ anchors,
    const float4* __restrict__ tboxes,
    const float4* __restrict__ bpreds,
    const unsigned long long* __restrict__ akeys,
    const unsigned long long* __restrict__ tkeys,
    double* __restrict__ cls_sum,
    int* __restrict__ n_pos,
    int* __restrict__ done_cnt,
    float* __restrict__ out)
{
    __shared__ int s_lab[256];
    __shared__ float s_red[8];
    __shared__ int s_flag;
    __shared__ double s_cls;
    __shared__ int s_np;

    const int tid = threadIdx.x;
    const int blk = blockIdx.x;
    const int a   = blk * 256 + tid;

    const unsigned long long akey = akeys[a];
    int lab = -1;
    if (akey != 0ull) {
        const unsigned int t = 0xFFFFFFFFu - (unsigned int)(akey & 0xFFFFFFFFull);
        lab = tlabels[t];
    }
    s_lab[tid] = lab;
    const unsigned long long bal = __ballot(akey != 0ull);
    if ((tid & 63) == 0) atomicAdd(n_pos, (int)__popcll(bal));
    __syncthreads();

    // focal loss over this block's 256 anchors x 21 classes (contiguous, coalesced)
    float acc = 0.f;
    const int base = blk * (256 * NC);
    for (int e = tid; e < 256 * NC; e += 256) {
        const int al = e / NC;            // magic-mul div
        const int c  = e - al * NC;
        const float x  = preds[base + e];
        const float t  = (s_lab[al] == c) ? 1.f : 0.f;
        const float ax = fabsf(x);
        const float u  = __expf(-ax);
        const float ce = fmaxf(x, 0.f) - x * t + __logf(1.f + u);
        const float p  = (x >= 0.f ? 1.f : u) / (1.f + u);
        const float pt = p * t + (1.f - p) * (1.f - t);
        const float at = 0.25f * t + 0.75f * (1.f - t);
        const float om = 1.f - pt;
        acc += at * om * om * ce;
    }
    for (int o = 32; o > 0; o >>= 1) acc += __shfl_down(acc, o);
    const int lane = tid & 63, wid = tid >> 6;
    if (lane == 0) s_red[wid] = acc;
    __syncthreads();
    if (tid == 0) {
        atomicAdd(cls_sum, (double)(s_red[0] + s_red[1] + s_red[2] + s_red[3]));
        __threadfence();
        const int old = atomicAdd(done_cnt, 1);
        s_flag = (old == (int)gridDim.x - 1);
    }
    __syncthreads();
    if (!s_flag) return;

    // ---- last block: regression loss + final combine ----
    if (tid == 0) {
        s_cls = atomicAdd(cls_sum, 0.0);  // coherent device-scope read
        s_np  = atomicAdd(n_pos, 0);
    }
    __syncthreads();

    float s = 0.f, m = 0.f;
    #pragma unroll
    for (int j = 0; j < 4; ++j) {
        const int t = tid + 256 * j;
        const unsigned long long key = tkeys[t];
        if (key != 0ull) {
            const unsigned int ga = 0xFFFFFFFFu - (unsigned int)(key & 0xFFFFFFFFull);
            const float4 tb = tboxes[t];
            const float4 abx = anchors[ga];
            const float4 pb = bpreds[ga];
            const float bw = tb.z - tb.x, bh = tb.w - tb.y;
            const float bcx = tb.x + 0.5f * bw, bcy = tb.y + 0.5f * bh;
            const float aw = abx.z - abx.x, ah = abx.w - abx.y;
            const float acx = abx.x + 0.5f * aw, acy = abx.y + 0.5f * ah;
            const float tx = (bcx - acx) / aw;
            const float ty = (bcy - acy) / ah;
            const float tw = logf(fmaxf(bw, 1e-8f) / aw);
            const float th = logf(fmaxf(bh, 1e-8f) / ah);
            s = smooth_l1(pb.x - tx) + smooth_l1(pb.y - ty) +
                smooth_l1(pb.z - tw) + smooth_l1(pb.w - th);
            m = 1.f;
        }
    }
    for (int o = 32; o > 0; o >>= 1) {
        s += __shfl_down(s, o);
        m += __shfl_down(m, o);
    }
    __syncthreads();          // s_red reuse
    if (lane == 0) { s_red[wid] = s; s_red[4 + wid] = m; }
    __syncthreads();
    if (tid == 0) {
        const float rs = s_red[0] + s_red[1] + s_red[2] + s_red[3];
        const float rm = s_red[4] + s_red[5] + s_red[6] + s_red[7];
        const float cls = (float)(s_cls / (double)s_np);
        const float reg = rs / (fmaxf(rm, 1.f) * 4.f);
        out[0] = cls + reg;
        out[1] = cls;
        out[2] = reg;
    }
}

extern "C" void kernel_launch(void* const* d_in, const int* in_sizes, int n_in,
                              void* d_out, int out_size, void* d_ws, size_t ws_size,
                              hipStream_t stream) {
    const float*  cls_preds = (const float*)d_in[0];
    const float4* bpreds    = (const float4*)d_in[1];
    const float4* anchors   = (const float4*)d_in[2];
    const float4* tboxes    = (const float4*)d_in[3];
    const int*    tlabels   = (const int*)d_in[4];

    char* ws = (char*)d_ws;
    double* cls_sum = (double*)(ws + 0);
    int*    n_pos   = (int*)(ws + 8);
    int*    done    = (int*)(ws + 12);
    unsigned long long* tkeys = (unsigned long long*)(ws + 16);
    unsigned long long* akeys = (unsigned long long*)(ws + 16 + NT * 8);

    hipMemsetAsync(d_ws, 0, 16 + NT * 8 + NA * 8, stream);

    k_match<<<dim3(ACH, TCH), 256, 0, stream>>>(anchors, tboxes, akeys, tkeys);
    k_cls_final<<<NA / 256, 256, 0, stream>>>(cls_preds, tlabels, anchors, tboxes,
                                              bpreds, akeys, tkeys,
                                              cls_sum, n_pos, done, (float*)d_out);
}

// Round 5
// 181.949 us; speedup vs baseline: 1.4159x; 1.4026x over previous
//
#include <hip/hip_runtime.h>
#include <stdint.h>

#define NA 98304
#define NT 1024
#define NC 21
#define ACH 384          // anchor chunks of 256
#define TCH 4            // target chunks of 256

// ws layout (same as R2, proven):
//   [0]   double cls_sum
//   [8]   int    n_pos
//   [12]  int    done_cnt
//   [16]         u64 tkeys[NT]    (8 KB)
//   [16+8192]    u64 akeys[NA]    (768 KB)
// memset covers [0, 16 + 8192 + NA*8)

__global__ __launch_bounds__(256) void k_match(
    const float4* __restrict__ anchors,
    const float4* __restrict__ tboxes,
    unsigned long long* __restrict__ akeys,
    unsigned long long* __restrict__ tkeys)
{
    __shared__ float4 s_t[256];
    __shared__ unsigned long long s_tk[256];   // per-block target-side winners

    const int tid   = threadIdx.x;
    const int ac    = blockIdx.x;
    const int tbase = blockIdx.y * 256;
    const int a     = ac * 256 + tid;

    s_t[tid]  = tboxes[tbase + tid];
    s_tk[tid] = 0ull;
    const float4 ab = anchors[a];
    __syncthreads();

    const float area_a = (ab.z - ab.x) * (ab.w - ab.y);

    // anchor-side running max: register-local, if-converted (R2-proven).
    float bi = 0.f, bu = 1.f;   // best (inter, union) => iou 0
    int bidx = 0;

    #pragma unroll 8
    for (int t = 0; t < 256; ++t) {
        const float4 tb = s_t[t];          // ds_read_b128 broadcast
        const float lx = fmaxf(ab.x, tb.x);
        const float ly = fmaxf(ab.y, tb.y);
        const float rx = fminf(ab.z, tb.z);
        const float ry = fminf(ab.w, tb.w);
        const float w  = fmaxf(rx - lx, 0.f);
        const float h  = fmaxf(ry - ly, 0.f);
        const float inter = w * h;
        const float sa  = (tb.z - tb.x) * (tb.w - tb.y);
        const float uni = (area_a + sa) - inter;

        // target-side: iou >= 0.5 pairs only (below-threshold can't matter).
        // Rare branch -> LDS atomic (cheap), NOT a device-scope global atomic.
        if (__builtin_expect(inter + inter >= uni, 0)) {
            const float iou = inter / uni;   // same fp32 rounding as reference
            atomicMax(&s_tk[t],
                      ((unsigned long long)__float_as_uint(iou) << 32) |
                      (unsigned long long)(0xFFFFFFFFu - (unsigned int)a)); // smaller a wins ties
        }

        // exact cross-mult compare; strict '>' keeps first index on ties
        const bool gt = inter * bu > bi * uni;
        bi   = gt ? inter : bi;
        bu   = gt ? uni   : bu;
        bidx = gt ? t     : bidx;
    }

    // anchor-side flush: only >=0.5 partial winners can matter (label else -1)
    if (bi + bi >= bu) {
        const float iou = bi / bu;
        const unsigned int tg = (unsigned int)(tbase + bidx);
        atomicMax(&akeys[a],
                  ((unsigned long long)__float_as_uint(iou) << 32) |
                  (unsigned long long)(0xFFFFFFFFu - tg));   // smaller t wins ties
    }

    // target-side flush: <=1 global atomic per matched target per block
    __syncthreads();
    const unsigned long long tk = s_tk[tid];
    if (tk != 0ull) atomicMax(&tkeys[tbase + tid], tk);
}

__device__ __forceinline__ float smooth_l1(float d) {
    const float ad = fabsf(d);
    return (ad < 1.f) ? 0.5f * d * d : ad - 0.5f;
}

// one block per 256 anchors; last-finishing block computes reg loss + writes out
__global__ __launch_bounds__(256) void k_cls_final(
    const float* __restrict__ preds,
    const int* __restrict__ tlabels,
    const float4* __restrict__ anchors,
    const float4* __restrict__ tboxes,
    const float4* __restrict__ bpreds,
    const unsigned long long* __restrict__ akeys,
    const unsigned long long* __restrict__ tkeys,
    double* __restrict__ cls_sum,
    int* __restrict__ n_pos,
    int* __restrict__ done_cnt,
    float* __restrict__ out)
{
    __shared__ int s_lab[256];
    __shared__ float s_red[8];
    __shared__ int s_flag;
    __shared__ double s_cls;
    __shared__ int s_np;

    const int tid = threadIdx.x;
    const int blk = blockIdx.x;
    const int a   = blk * 256 + tid;

    const unsigned long long akey = akeys[a];
    int lab = -1;
    if (akey != 0ull) {
        const unsigned int t = 0xFFFFFFFFu - (unsigned int)(akey & 0xFFFFFFFFull);
        lab = tlabels[t];
    }
    s_lab[tid] = lab;
    const unsigned long long bal = __ballot(akey != 0ull);
    if ((tid & 63) == 0) atomicAdd(n_pos, (int)__popcll(bal));
    __syncthreads();

    // focal loss over this block's 256 anchors x 21 classes (contiguous, coalesced)
    float acc = 0.f;
    const int base = blk * (256 * NC);
    for (int e = tid; e < 256 * NC; e += 256) {
        const int al = e / NC;            // magic-mul div
        const int c  = e - al * NC;
        const float x  = preds[base + e];
        const float t  = (s_lab[al] == c) ? 1.f : 0.f;
        const float ax = fabsf(x);
        const float u  = __expf(-ax);
        const float ce = fmaxf(x, 0.f) - x * t + __logf(1.f + u);
        const float p  = (x >= 0.f ? 1.f : u) / (1.f + u);
        const float pt = p * t + (1.f - p) * (1.f - t);
        const float at = 0.25f * t + 0.75f * (1.f - t);
        const float om = 1.f - pt;
        acc += at * om * om * ce;
    }
    for (int o = 32; o > 0; o >>= 1) acc += __shfl_down(acc, o);
    const int lane = tid & 63, wid = tid >> 6;
    if (lane == 0) s_red[wid] = acc;
    __syncthreads();
    if (tid == 0) {
        atomicAdd(cls_sum, (double)(s_red[0] + s_red[1] + s_red[2] + s_red[3]));
        __threadfence();
        const int old = atomicAdd(done_cnt, 1);
        s_flag = (old == (int)gridDim.x - 1);
    }
    __syncthreads();
    if (!s_flag) return;

    // ---- last block: regression loss + final combine ----
    if (tid == 0) {
        s_cls = atomicAdd(cls_sum, 0.0);  // coherent device-scope read
        s_np  = atomicAdd(n_pos, 0);
    }
    __syncthreads();

    float s = 0.f, m = 0.f;
    #pragma unroll
    for (int j = 0; j < 4; ++j) {
        const int t = tid + 256 * j;
        const unsigned long long key = tkeys[t];
        if (key != 0ull) {
            const unsigned int ga = 0xFFFFFFFFu - (unsigned int)(key & 0xFFFFFFFFull);
            const float4 tb = tboxes[t];
            const float4 abx = anchors[ga];
            const float4 pb = bpreds[ga];
            const float bw = tb.z - tb.x, bh = tb.w - tb.y;
            const float bcx = tb.x + 0.5f * bw, bcy = tb.y + 0.5f * bh;
            const float aw = abx.z - abx.x, ah = abx.w - abx.y;
            const float acx = abx.x + 0.5f * aw, acy = abx.y + 0.5f * ah;
            const float tx = (bcx - acx) / aw;
            const float ty = (bcy - acy) / ah;
            const float tw = logf(fmaxf(bw, 1e-8f) / aw);
            const float th = logf(fmaxf(bh, 1e-8f) / ah);
            s = smooth_l1(pb.x - tx) + smooth_l1(pb.y - ty) +
                smooth_l1(pb.z - tw) + smooth_l1(pb.w - th);
            m = 1.f;
        }
    }
    for (int o = 32; o > 0; o >>= 1) {
        s += __shfl_down(s, o);
        m += __shfl_down(m, o);
    }
    __syncthreads();          // s_red reuse
    if (lane == 0) { s_red[wid] = s; s_red[4 + wid] = m; }
    __syncthreads();
    if (tid == 0) {
        const float rs = s_red[0] + s_red[1] + s_red[2] + s_red[3];
        const float rm = s_red[4] + s_red[5] + s_red[6] + s_red[7];
        const float cls = (float)(s_cls / (double)s_np);
        const float reg = rs / (fmaxf(rm, 1.f) * 4.f);
        out[0] = cls + reg;
        out[1] = cls;
        out[2] = reg;
    }
}

extern "C" void kernel_launch(void* const* d_in, const int* in_sizes, int n_in,
                              void* d_out, int out_size, void* d_ws, size_t ws_size,
                              hipStream_t stream) {
    const float*  cls_preds = (const float*)d_in[0];
    const float4* bpreds    = (const float4*)d_in[1];
    const float4* anchors   = (const float4*)d_in[2];
    const float4* tboxes    = (const float4*)d_in[3];
    const int*    tlabels   = (const int*)d_in[4];

    char* ws = (char*)d_ws;
    double* cls_sum = (double*)(ws + 0);
    int*    n_pos   = (int*)(ws + 8);
    int*    done    = (int*)(ws + 12);
    unsigned long long* tkeys = (unsigned long long*)(ws + 16);
    unsigned long long* akeys = (unsigned long long*)(ws + 16 + NT * 8);

    hipMemsetAsync(d_ws, 0, 16 + NT * 8 + NA * 8, stream);

    k_match<<<dim3(ACH, TCH), 256, 0, stream>>>(anchors, tboxes, akeys, tkeys);
    k_cls_final<<<NA / 256, 256, 0, stream>>>(cls_preds, tlabels, anchors, tboxes,
                                              bpreds, akeys, tkeys,
                                              cls_sum, n_pos, done, (float*)d_out);
}

// Round 6
// 160.812 us; speedup vs baseline: 1.6019x; 1.1314x over previous
//
#include <hip/hip_runtime.h>
#include <stdint.h>

#define NA 98304
#define NT 1024
#define NC 21
#define ACH 192          // anchor chunks of 512 (2 per thread)
#define TCH 8            // target chunks of 128

// ws layout:
//   [0]   double cls_sum
//   [8]   int    n_pos
//   [12]  int    done_cnt
//   [16]         u64 tkeys[NT]    (8 KB)
//   [16+8192]    u64 akeys[NA]    (768 KB)
// memset covers [0, 16 + 8192 + NA*8)

__global__ __launch_bounds__(256) void k_match(
    const float4* __restrict__ anchors,
    const float4* __restrict__ tboxes,
    unsigned long long* __restrict__ akeys,
    unsigned long long* __restrict__ tkeys)
{
    __shared__ float4 s_t[128];
    __shared__ unsigned long long s_tk[128];   // per-block target-side winners

    const int tid   = threadIdx.x;
    const int tbase = blockIdx.y * 128;
    const int a0    = blockIdx.x * 512 + tid;
    const int a1    = a0 + 256;

    if (tid < 128) {
        s_t[tid]  = tboxes[tbase + tid];
        s_tk[tid] = 0ull;
    }
    const float4 A0 = anchors[a0];
    const float4 A1 = anchors[a1];
    __syncthreads();

    const float ar0 = (A0.z - A0.x) * (A0.w - A0.y);
    const float ar1 = (A1.z - A1.x) * (A1.w - A1.y);

    // Anchor-side best tracked ONLY among iou>=0.5 pairs (below-threshold
    // can't matter: label would be -1). Compare rounded fp32 iou with strict
    // '>' in ascending t == reference argmax-first-index semantics exactly.
    float b0 = 0.f, b1 = 0.f;
    int   i0 = -1,  i1 = -1;

    #pragma unroll 4
    for (int t = 0; t < 128; ++t) {
        const float4 tb = s_t[t];          // one broadcast b128, shared by 2 anchors
        const float sa = (tb.z - tb.x) * (tb.w - tb.y);

        // ---- anchor 0 ----
        {
            const float lx = fmaxf(A0.x, tb.x);
            const float ly = fmaxf(A0.y, tb.y);
            const float rx = fminf(A0.z, tb.z);
            const float ry = fminf(A0.w, tb.w);
            const float w  = fmaxf(rx - lx, 0.f);
            const float h  = fmaxf(ry - ly, 0.f);
            const float inter = w * h;
            const float uni = (ar0 + sa) - inter;
            if (__builtin_expect(inter + inter >= uni, 0)) {
                const float iou = inter / uni;
                if (iou > b0) { b0 = iou; i0 = t; }
                atomicMax(&s_tk[t],
                          ((unsigned long long)__float_as_uint(iou) << 32) |
                          (unsigned long long)(0xFFFFFFFFu - (unsigned int)a0));
            }
        }
        // ---- anchor 1 (independent chain: ILP) ----
        {
            const float lx = fmaxf(A1.x, tb.x);
            const float ly = fmaxf(A1.y, tb.y);
            const float rx = fminf(A1.z, tb.z);
            const float ry = fminf(A1.w, tb.w);
            const float w  = fmaxf(rx - lx, 0.f);
            const float h  = fmaxf(ry - ly, 0.f);
            const float inter = w * h;
            const float uni = (ar1 + sa) - inter;
            if (__builtin_expect(inter + inter >= uni, 0)) {
                const float iou = inter / uni;
                if (iou > b1) { b1 = iou; i1 = t; }
                atomicMax(&s_tk[t],
                          ((unsigned long long)__float_as_uint(iou) << 32) |
                          (unsigned long long)(0xFFFFFFFFu - (unsigned int)a1));
            }
        }
    }

    if (i0 >= 0)
        atomicMax(&akeys[a0],
                  ((unsigned long long)__float_as_uint(b0) << 32) |
                  (unsigned long long)(0xFFFFFFFFu - (unsigned int)(tbase + i0)));
    if (i1 >= 0)
        atomicMax(&akeys[a1],
                  ((unsigned long long)__float_as_uint(b1) << 32) |
                  (unsigned long long)(0xFFFFFFFFu - (unsigned int)(tbase + i1)));

    __syncthreads();
    if (tid < 128) {
        const unsigned long long tk = s_tk[tid];
        if (tk != 0ull) atomicMax(&tkeys[tbase + tid], tk);
    }
}

__device__ __forceinline__ float smooth_l1(float d) {
    const float ad = fabsf(d);
    return (ad < 1.f) ? 0.5f * d * d : ad - 0.5f;
}

// one block per 256 anchors; last-finishing block computes reg loss + writes out
__global__ __launch_bounds__(256) void k_cls_final(
    const float* __restrict__ preds,
    const int* __restrict__ tlabels,
    const float4* __restrict__ anchors,
    const float4* __restrict__ tboxes,
    const float4* __restrict__ bpreds,
    const unsigned long long* __restrict__ akeys,
    const unsigned long long* __restrict__ tkeys,
    double* __restrict__ cls_sum,
    int* __restrict__ n_pos,
    int* __restrict__ done_cnt,
    float* __restrict__ out)
{
    __shared__ int s_lab[256];
    __shared__ float s_red[8];
    __shared__ int s_flag;
    __shared__ double s_cls;
    __shared__ int s_np;

    const int tid = threadIdx.x;
    const int blk = blockIdx.x;
    const int a   = blk * 256 + tid;

    const unsigned long long akey = akeys[a];
    int lab = -1;
    if (akey != 0ull) {
        const unsigned int t = 0xFFFFFFFFu - (unsigned int)(akey & 0xFFFFFFFFull);
        lab = tlabels[t];
    }
    s_lab[tid] = lab;
    const unsigned long long bal = __ballot(akey != 0ull);
    if ((tid & 63) == 0) atomicAdd(n_pos, (int)__popcll(bal));
    __syncthreads();

    // focal loss over this block's 256 anchors x 21 classes (contiguous, coalesced)
    float acc = 0.f;
    const int base = blk * (256 * NC);
    for (int e = tid; e < 256 * NC; e += 256) {
        const int al = e / NC;            // magic-mul div
        const int c  = e - al * NC;
        const float x  = preds[base + e];
        const float t  = (s_lab[al] == c) ? 1.f : 0.f;
        const float ax = fabsf(x);
        const float u  = __expf(-ax);
        const float ce = fmaxf(x, 0.f) - x * t + __logf(1.f + u);
        const float p  = (x >= 0.f ? 1.f : u) / (1.f + u);
        const float pt = p * t + (1.f - p) * (1.f - t);
        const float at = 0.25f * t + 0.75f * (1.f - t);
        const float om = 1.f - pt;
        acc += at * om * om * ce;
    }
    for (int o = 32; o > 0; o >>= 1) acc += __shfl_down(acc, o);
    const int lane = tid & 63, wid = tid >> 6;
    if (lane == 0) s_red[wid] = acc;
    __syncthreads();
    if (tid == 0) {
        atomicAdd(cls_sum, (double)(s_red[0] + s_red[1] + s_red[2] + s_red[3]));
        __threadfence();
        const int old = atomicAdd(done_cnt, 1);
        s_flag = (old == (int)gridDim.x - 1);
    }
    __syncthreads();
    if (!s_flag) return;

    // ---- last block: regression loss + final combine ----
    if (tid == 0) {
        s_cls = atomicAdd(cls_sum, 0.0);  // coherent device-scope read
        s_np  = atomicAdd(n_pos, 0);
    }
    __syncthreads();

    float s = 0.f, m = 0.f;
    #pragma unroll
    for (int j = 0; j < 4; ++j) {
        const int t = tid + 256 * j;
        const unsigned long long key = tkeys[t];
        if (key != 0ull) {
            const unsigned int ga = 0xFFFFFFFFu - (unsigned int)(key & 0xFFFFFFFFull);
            const float4 tb = tboxes[t];
            const float4 abx = anchors[ga];
            const float4 pb = bpreds[ga];
            const float bw = tb.z - tb.x, bh = tb.w - tb.y;
            const float bcx = tb.x + 0.5f * bw, bcy = tb.y + 0.5f * bh;
            const float aw = abx.z - abx.x, ah = abx.w - abx.y;
            const float acx = abx.x + 0.5f * aw, acy = abx.y + 0.5f * ah;
            const float tx = (bcx - acx) / aw;
            const float ty = (bcy - acy) / ah;
            const float tw = logf(fmaxf(bw, 1e-8f) / aw);
            const float th = logf(fmaxf(bh, 1e-8f) / ah);
            s = smooth_l1(pb.x - tx) + smooth_l1(pb.y - ty) +
                smooth_l1(pb.z - tw) + smooth_l1(pb.w - th);
            m = 1.f;
        }
    }
    for (int o = 32; o > 0; o >>= 1) {
        s += __shfl_down(s, o);
        m += __shfl_down(m, o);
    }
    __syncthreads();          // s_red reuse
    if (lane == 0) { s_red[wid] = s; s_red[4 + wid] = m; }
    __syncthreads();
    if (tid == 0) {
        const float rs = s_red[0] + s_red[1] + s_red[2] + s_red[3];
        const float rm = s_red[4] + s_red[5] + s_red[6] + s_red[7];
        const float cls = (float)(s_cls / (double)s_np);
        const float reg = rs / (fmaxf(rm, 1.f) * 4.f);
        out[0] = cls + reg;
        out[1] = cls;
        out[2] = reg;
    }
}

extern "C" void kernel_launch(void* const* d_in, const int* in_sizes, int n_in,
                              void* d_out, int out_size, void* d_ws, size_t ws_size,
                              hipStream_t stream) {
    const float*  cls_preds = (const float*)d_in[0];
    const float4* bpreds    = (const float4*)d_in[1];
    const float4* anchors   = (const float4*)d_in[2];
    const float4* tboxes    = (const float4*)d_in[3];
    const int*    tlabels   = (const int*)d_in[4];

    char* ws = (char*)d_ws;
    double* cls_sum = (double*)(ws + 0);
    int*    n_pos   = (int*)(ws + 8);
    int*    done    = (int*)(ws + 12);
    unsigned long long* tkeys = (unsigned long long*)(ws + 16);
    unsigned long long* akeys = (unsigned long long*)(ws + 16 + NT * 8);

    hipMemsetAsync(d_ws, 0, 16 + NT * 8 + NA * 8, stream);

    k_match<<<dim3(ACH, TCH), 256, 0, stream>>>(anchors, tboxes, akeys, tkeys);
    k_cls_final<<<NA / 256, 256, 0, stream>>>(cls_preds, tlabels, anchors, tboxes,
                                              bpreds, akeys, tkeys,
                                              cls_sum, n_pos, done, (float*)d_out);
}